// Round 11
// baseline (75.544 us; speedup 1.0000x reference)
//
#include <hip/hip_runtime.h>

// HFOnlyAttn MFMA v9: head-split wave pairs. Each 16-px tile is handled by
// TWO waves: half 0 computes heads {0,1}, half 1 computes heads {2,3}; both
// load the same X (dup reads hit L3). y frags meet in a shared 6KB tile
// buffer (sp=h>>1 gives a disjoint split), one __syncthreads, then each half
// does proj for its two m-blocks. Halves per-wave critical path, doubles
// wave count (16384 waves) -> real pipelining in a latency-bound regime.
// qkv^T = Wqkv^T (192x64) @ X^T (64 x px); 4-head 3x3 softmax in-register;
// y -> tile LDS relayout -> proj: out^T = Wproj^T @ y^T; residual from Xf.
// mfma_f32_16x16x32_bf16:  A: lane l -> row=l&15, k=(l>>4)*8+{0..7}
//                          B: lane l -> col=l&15, k=(l>>4)*8+{0..7}
//                          C: lane l -> col=l&15, row=(l>>4)*4+reg
// Residual extraction: channel b*64+m*16+g*4+j of pixel c lives in
// Xf[b][m>>1], element (g&1)*4+j, on lane ((m&1)*2+(g>>1))*16+c.

typedef __attribute__((ext_vector_type(8))) short bf16x8;
typedef __attribute__((ext_vector_type(4))) float f32x4;

constexpr int kHW = 16384;
constexpr int kC = 192;

__device__ __forceinline__ unsigned short f2bf(float f) {
  unsigned int u = __float_as_uint(f);
  return (unsigned short)((u + 0x7fffu + ((u >> 16) & 1u)) >> 16);  // RNE
}

// kernel0: pack Wqkv^T/Wproj^T A-fragments into ws (24 + 8 frags x 1024B).
__global__ void pack_weights(const float* __restrict__ Wqkv,
                             const float* __restrict__ Wproj,
                             unsigned char* __restrict__ wsc) {
  const int tid = threadIdx.x;
  const int wid = tid >> 6;
  const int l = tid & 63;
  const int c = l & 15;
  const int g = l >> 4;
  for (int f = wid; f < 24; f += 4) {
    const int m = f >> 1, s = f & 1;
    const int row = m * 16 + c;
    const int k0 = s * 32 + g * 8;
    bf16x8 wf;
#pragma unroll
    for (int j = 0; j < 8; ++j) wf[j] = (short)f2bf(Wqkv[(k0 + j) * 192 + row]);
    *(bf16x8*)(wsc + f * 1024 + l * 16) = wf;
  }
  for (int f = wid; f < 8; f += 4) {
    const int m = f >> 1, s = f & 1;
    const int row = m * 16 + c;
    const int k0 = s * 32 + g * 8;
    bf16x8 wf;
#pragma unroll
    for (int j = 0; j < 8; ++j) wf[j] = (short)f2bf(Wproj[(k0 + j) * 64 + row]);
    *(bf16x8*)(wsc + 24576 + f * 1024 + l * 16) = wf;
  }
}

__global__ __launch_bounds__(256, 6) void hfattn_mfma9(
    const float* __restrict__ hf,
    const unsigned char* __restrict__ wfr,  // packed weight frags (32KB)
    const float* __restrict__ bproj,
    const float* __restrict__ rscale,
    float* __restrict__ out) {
  // LDS: 2 tiles x 6KB y-relayout buffers (shared by the tile's wave pair).
  __shared__ char smem[12288];

  const int tid = threadIdx.x;
  const int wid = tid >> 6;
  const int l = tid & 63;
  const int c = l & 15;   // MFMA col (pixel slot)
  const int g = l >> 4;   // 4-lane group
  const int tile = wid >> 1;  // 0,1: which 16-px tile of this block
  const int half = wid & 1;   // 0: heads {0,1}; 1: heads {2,3}

  char* const yBase = smem + tile * 6144;
  const f32x4 zz = {0.f, 0.f, 0.f, 0.f};
  const bf16x8* const wp = (const bf16x8*)wfr;

  const int pxB = blockIdx.x * 32 + tile * 16;  // 4096 blocks x 32 px
  const int b8 = pxB >> 14;
  const int blkBase = b8 * (kC * kHW);
  const int hw = (pxB & (kHW - 1)) + c;
  const float* __restrict__ hfp = hf + blkBase + hw;
  float* __restrict__ outp = out + blkBase + hw;

  const float rv = rscale[0];

  // ---------- phase 1: issue ALL 48 X loads, fence, convert ----------
  float xr[3][2][8];
#pragma unroll
  for (int b = 0; b < 3; ++b)
#pragma unroll
    for (int s = 0; s < 2; ++s)
#pragma unroll
      for (int j = 0; j < 8; ++j)
        xr[b][s][j] = hfp[(b * 64 + s * 32 + g * 8 + j) * kHW];
  __builtin_amdgcn_sched_barrier(0);  // all 48 loads issue before any convert

  bf16x8 Xf[3][2];
#pragma unroll
  for (int b = 0; b < 3; ++b)
#pragma unroll
    for (int s = 0; s < 2; ++s) {
      bf16x8 xf;
#pragma unroll
      for (int j = 0; j < 8; ++j) xf[j] = (short)f2bf(xr[b][s][j]);
      Xf[b][s] = xf;
    }

  // ---------- this wave's two heads: q,k -> softmax -> v -> y -> LDS ----------
#pragma unroll
  for (int hh = 0; hh < 2; ++hh) {
    const int h = half * 2 + hh;
    const bf16x8 qA0 = wp[(h * 2 + 0) * 64 + l];
    const bf16x8 qA1 = wp[(h * 2 + 1) * 64 + l];
    const bf16x8 kA0 = wp[((4 + h) * 2 + 0) * 64 + l];
    const bf16x8 kA1 = wp[((4 + h) * 2 + 1) * 64 + l];
    f32x4 q[3], k[3];
#pragma unroll
    for (int b = 0; b < 3; ++b) {
      q[b] = __builtin_amdgcn_mfma_f32_16x16x32_bf16(qA0, Xf[b][0], zz, 0, 0, 0);
      q[b] = __builtin_amdgcn_mfma_f32_16x16x32_bf16(qA1, Xf[b][1], q[b], 0, 0, 0);
      k[b] = __builtin_amdgcn_mfma_f32_16x16x32_bf16(kA0, Xf[b][0], zz, 0, 0, 0);
      k[b] = __builtin_amdgcn_mfma_f32_16x16x32_bf16(kA1, Xf[b][1], k[b], 0, 0, 0);
    }
    // scores + softmax (reduce over the 4-lane row-groups)
    float P[3][3];
#pragma unroll
    for (int r1 = 0; r1 < 3; ++r1) {
      float sc[3];
#pragma unroll
      for (int r2 = 0; r2 < 3; ++r2) {
        float d = q[r1][0] * k[r2][0] + q[r1][1] * k[r2][1] +
                  q[r1][2] * k[r2][2] + q[r1][3] * k[r2][3];
        d += __shfl_xor(d, 16);
        d += __shfl_xor(d, 32);
        sc[r2] = d * 0.25f;
      }
      const float mx = fmaxf(sc[0], fmaxf(sc[1], sc[2]));
      const float e0 = __expf(sc[0] - mx);
      const float e1 = __expf(sc[1] - mx);
      const float e2 = __expf(sc[2] - mx);
      const float inv = 1.f / (e0 + e1 + e2);
      P[r1][0] = e0 * inv;
      P[r1][1] = e1 * inv;
      P[r1][2] = e2 * inv;
    }
    // v
    const bf16x8 vA0 = wp[((8 + h) * 2 + 0) * 64 + l];
    const bf16x8 vA1 = wp[((8 + h) * 2 + 1) * 64 + l];
    f32x4 v[3];
#pragma unroll
    for (int b = 0; b < 3; ++b) {
      v[b] = __builtin_amdgcn_mfma_f32_16x16x32_bf16(vA0, Xf[b][0], zz, 0, 0, 0);
      v[b] = __builtin_amdgcn_mfma_f32_16x16x32_bf16(vA1, Xf[b][1], v[b], 0, 0, 0);
    }
    // y = P @ v, write to tile LDS in proj-B-frag layout (sp split by half).
    const int sp = h >> 1;
    const int gp = (h & 1) * 2 + (g >> 1);
    const int wslot = (gp * 16 + c) * 16 + (g & 1) * 8;
#pragma unroll
    for (int r1 = 0; r1 < 3; ++r1) {
      float y0 = P[r1][0] * v[0][0] + P[r1][1] * v[1][0] + P[r1][2] * v[2][0];
      float y1 = P[r1][0] * v[0][1] + P[r1][1] * v[1][1] + P[r1][2] * v[2][1];
      float y2 = P[r1][0] * v[0][2] + P[r1][1] * v[1][2] + P[r1][2] * v[2][2];
      float y3 = P[r1][0] * v[0][3] + P[r1][1] * v[1][3] + P[r1][2] * v[2][3];
      uint2 pk;
      pk.x = (unsigned)f2bf(y0) | ((unsigned)f2bf(y1) << 16);
      pk.y = (unsigned)f2bf(y2) | ((unsigned)f2bf(y3) << 16);
      *(uint2*)(yBase + (r1 * 2 + sp) * 1024 + wslot) = pk;
    }
  }

  __syncthreads();  // tile's other half must finish its y frags

  // ---------- epilogue: proj + residual-from-Xf for this half's two m ----------
#pragma unroll
  for (int b = 0; b < 3; ++b) {
    const bf16x8 yB0 = *(bf16x8*)(yBase + (b * 2 + 0) * 1024 + l * 16);
    const bf16x8 yB1 = *(bf16x8*)(yBase + (b * 2 + 1) * 1024 + l * 16);
#pragma unroll
    for (int mm = 0; mm < 2; ++mm) {
      const int m = half * 2 + mm;
      const bf16x8 pA0 = wp[(24 + m * 2 + 0) * 64 + l];
      const bf16x8 pA1 = wp[(24 + m * 2 + 1) * 64 + l];
      f32x4 o = __builtin_amdgcn_mfma_f32_16x16x32_bf16(pA0, yB0, zz, 0, 0, 0);
      o = __builtin_amdgcn_mfma_f32_16x16x32_bf16(pA1, yB1, o, 0, 0, 0);

      const float4 bj = *(const float4*)(bproj + m * 16 + g * 4);
      const float bias_[4] = {bj.x, bj.y, bj.z, bj.w};

      // residual from Xf via wave shuffles (all transient)
      union {
        bf16x8 v;
        unsigned u[4];
      } su;
      su.v = Xf[b][m >> 1];
      const int hl = ((m & 1) * 2 + (g >> 1)) * 16 + c;
      const unsigned w0 = (unsigned)__shfl((int)su.u[0], hl, 64);
      const unsigned w1 = (unsigned)__shfl((int)su.u[1], hl, 64);
      const unsigned w2 = (unsigned)__shfl((int)su.u[2], hl, 64);
      const unsigned w3 = (unsigned)__shfl((int)su.u[3], hl, 64);
      const unsigned lo = (g & 1) ? w2 : w0;  // channels j=0,1
      const unsigned hi = (g & 1) ? w3 : w1;  // channels j=2,3
      float res[4];
      res[0] = __uint_as_float(lo << 16);
      res[1] = __uint_as_float(lo & 0xffff0000u);
      res[2] = __uint_as_float(hi << 16);
      res[3] = __uint_as_float(hi & 0xffff0000u);

#pragma unroll
      for (int j = 0; j < 4; ++j) {
        outp[(b * 64 + m * 16 + g * 4 + j) * kHW] =
            fmaf(rv, o[j] + bias_[j], res[j]);
      }
    }
  }
}

extern "C" void kernel_launch(void* const* d_in, const int* in_sizes, int n_in,
                              void* d_out, int out_size, void* d_ws,
                              size_t ws_size, hipStream_t stream) {
  const float* hf = (const float*)d_in[0];
  const float* Wqkv = (const float*)d_in[1];
  const float* Wproj = (const float*)d_in[2];
  const float* bproj = (const float*)d_in[3];
  const float* rscale = (const float*)d_in[4];
  float* out = (float*)d_out;
  unsigned char* wsc = (unsigned char*)d_ws;

  hipLaunchKernelGGL(pack_weights, dim3(1), dim3(256), 0, stream, Wqkv, Wproj,
                     wsc);

  const int npix = in_sizes[0] / kC;  // 131072
  const int nblocks = npix / 32;      // 4096
  hipLaunchKernelGGL(hfattn_mfma9, dim3(nblocks), dim3(256), 0, stream, hf, wsc,
                     bproj, rscale, out);
}

// Round 12
// 48.514 us; speedup vs baseline: 1.5572x; 1.5572x over previous
//
#include <hip/hip_runtime.h>

// HFOnlyAttn MFMA v10 = v7 + weight frags staged to LDS (32KB, once per
// block, global_load_lds + 1 barrier; per-head fetches become pipelined
// ds_read_b128 instead of per-wave L2 round-trips) + y-relayout via v4's
// verified in-register shuffles (no y-LDS). LDS 32KB -> 4 blocks/CU at
// launch_bounds(256,4); the LDS footprint also pins the compiler's
// occupancy target at 4 waves/SIMD -> VGPR budget 128 -> no spill (v4/v9's
// failure mode was LDS~0 -> compiler chases 8 waves/SIMD -> forced spill).
// qkv^T = Wqkv^T (192x64) @ X^T (64 x px); 4-head 3x3 softmax in-register;
// y relayout via shuffles; out^T = Wproj^T @ y^T; residual from Xf.
// mfma_f32_16x16x32_bf16:  A: lane l -> row=l&15, k=(l>>4)*8+{0..7}
//                          B: lane l -> col=l&15, k=(l>>4)*8+{0..7}
//                          C: lane l -> col=l&15, row=(l>>4)*4+reg
// Relayout (v4-verified): proj-B-frag(sp) lane(g,c) elem e = ych sp*32+g*8+e;
// holder lane ((g&1)*2+(e>>2))*16+c, head sp*2+(g>>1), reg e&3.
// Residual: channel b*64+m*16+g*4+j of pixel c lives in Xf[b][m>>1],
// element (g&1)*4+j, on lane ((m&1)*2+(g>>1))*16+c.

typedef __attribute__((ext_vector_type(8))) short bf16x8;
typedef __attribute__((ext_vector_type(4))) float f32x4;

constexpr int kHW = 16384;
constexpr int kC = 192;

__device__ __forceinline__ unsigned short f2bf(float f) {
  unsigned int u = __float_as_uint(f);
  return (unsigned short)((u + 0x7fffu + ((u >> 16) & 1u)) >> 16);  // RNE
}

// kernel0: pack Wqkv^T/Wproj^T A-fragments into ws (24 + 8 frags x 1024B).
__global__ void pack_weights(const float* __restrict__ Wqkv,
                             const float* __restrict__ Wproj,
                             unsigned char* __restrict__ wsc) {
  const int tid = threadIdx.x;
  const int wid = tid >> 6;
  const int l = tid & 63;
  const int c = l & 15;
  const int g = l >> 4;
  for (int f = wid; f < 24; f += 4) {
    const int m = f >> 1, s = f & 1;
    const int row = m * 16 + c;
    const int k0 = s * 32 + g * 8;
    bf16x8 wf;
#pragma unroll
    for (int j = 0; j < 8; ++j) wf[j] = (short)f2bf(Wqkv[(k0 + j) * 192 + row]);
    *(bf16x8*)(wsc + f * 1024 + l * 16) = wf;
  }
  for (int f = wid; f < 8; f += 4) {
    const int m = f >> 1, s = f & 1;
    const int row = m * 16 + c;
    const int k0 = s * 32 + g * 8;
    bf16x8 wf;
#pragma unroll
    for (int j = 0; j < 8; ++j) wf[j] = (short)f2bf(Wproj[(k0 + j) * 64 + row]);
    *(bf16x8*)(wsc + 24576 + f * 1024 + l * 16) = wf;
  }
}

// One head: q,k MFMAs -> 3x3 softmax -> v MFMAs -> y packs (3 uint2).
// Weights read from LDS (ds_read_b128, lgkmcnt-pipelined).
template <int H>
__device__ __forceinline__ void head_compute(const char* wl, int l,
                                             const bf16x8 (&Xf)[3][2],
                                             uint2 (&pk)[3]) {
  const f32x4 zz = {0.f, 0.f, 0.f, 0.f};
  const bf16x8 qA0 = *(const bf16x8*)(wl + (H * 2 + 0) * 1024 + l * 16);
  const bf16x8 qA1 = *(const bf16x8*)(wl + (H * 2 + 1) * 1024 + l * 16);
  const bf16x8 kA0 = *(const bf16x8*)(wl + ((4 + H) * 2 + 0) * 1024 + l * 16);
  const bf16x8 kA1 = *(const bf16x8*)(wl + ((4 + H) * 2 + 1) * 1024 + l * 16);
  f32x4 q[3], k[3];
#pragma unroll
  for (int b = 0; b < 3; ++b) {
    q[b] = __builtin_amdgcn_mfma_f32_16x16x32_bf16(qA0, Xf[b][0], zz, 0, 0, 0);
    q[b] = __builtin_amdgcn_mfma_f32_16x16x32_bf16(qA1, Xf[b][1], q[b], 0, 0, 0);
    k[b] = __builtin_amdgcn_mfma_f32_16x16x32_bf16(kA0, Xf[b][0], zz, 0, 0, 0);
    k[b] = __builtin_amdgcn_mfma_f32_16x16x32_bf16(kA1, Xf[b][1], k[b], 0, 0, 0);
  }
  float P[3][3];
#pragma unroll
  for (int r1 = 0; r1 < 3; ++r1) {
    float sc[3];
#pragma unroll
    for (int r2 = 0; r2 < 3; ++r2) {
      float d = q[r1][0] * k[r2][0] + q[r1][1] * k[r2][1] +
                q[r1][2] * k[r2][2] + q[r1][3] * k[r2][3];
      d += __shfl_xor(d, 16);
      d += __shfl_xor(d, 32);
      sc[r2] = d * 0.25f;
    }
    const float mx = fmaxf(sc[0], fmaxf(sc[1], sc[2]));
    const float e0 = __expf(sc[0] - mx);
    const float e1 = __expf(sc[1] - mx);
    const float e2 = __expf(sc[2] - mx);
    const float inv = 1.f / (e0 + e1 + e2);
    P[r1][0] = e0 * inv;
    P[r1][1] = e1 * inv;
    P[r1][2] = e2 * inv;
  }
  const bf16x8 vA0 = *(const bf16x8*)(wl + ((8 + H) * 2 + 0) * 1024 + l * 16);
  const bf16x8 vA1 = *(const bf16x8*)(wl + ((8 + H) * 2 + 1) * 1024 + l * 16);
  f32x4 v[3];
#pragma unroll
  for (int b = 0; b < 3; ++b) {
    v[b] = __builtin_amdgcn_mfma_f32_16x16x32_bf16(vA0, Xf[b][0], zz, 0, 0, 0);
    v[b] = __builtin_amdgcn_mfma_f32_16x16x32_bf16(vA1, Xf[b][1], v[b], 0, 0, 0);
  }
#pragma unroll
  for (int r1 = 0; r1 < 3; ++r1) {
    f32x4 y = P[r1][0] * v[0] + P[r1][1] * v[1] + P[r1][2] * v[2];
    uint2 p;
    p.x = (unsigned)f2bf(y[0]) | ((unsigned)f2bf(y[1]) << 16);
    p.y = (unsigned)f2bf(y[2]) | ((unsigned)f2bf(y[3]) << 16);
    pk[r1] = p;
  }
}

// Build proj-B-frag for K-step sp from the packs of heads (2sp, 2sp+1).
__device__ __forceinline__ bf16x8 build_frag(uint2 pkA, uint2 pkB, int srcA,
                                             bool hi) {
  uint2 a0, a1, b0, b1;
  a0.x = (unsigned)__shfl((int)pkA.x, srcA, 64);
  a0.y = (unsigned)__shfl((int)pkA.y, srcA, 64);
  a1.x = (unsigned)__shfl((int)pkB.x, srcA, 64);
  a1.y = (unsigned)__shfl((int)pkB.y, srcA, 64);
  const int srcB = srcA + 16;
  b0.x = (unsigned)__shfl((int)pkA.x, srcB, 64);
  b0.y = (unsigned)__shfl((int)pkA.y, srcB, 64);
  b1.x = (unsigned)__shfl((int)pkB.x, srcB, 64);
  b1.y = (unsigned)__shfl((int)pkB.y, srcB, 64);
  const uint2 lo = hi ? a1 : a0;
  const uint2 hi2 = hi ? b1 : b0;
  union {
    unsigned u[4];
    bf16x8 v;
  } r;
  r.u[0] = lo.x;
  r.u[1] = lo.y;
  r.u[2] = hi2.x;
  r.u[3] = hi2.y;
  return r.v;
}

__global__ __launch_bounds__(256, 4) void hfattn_mfma10(
    const float* __restrict__ hf,
    const unsigned char* __restrict__ wfr,  // packed weight frags (32KB)
    const float* __restrict__ bproj,
    const float* __restrict__ rscale,
    float* __restrict__ out) {
  // LDS: the 32KB weight-fragment table, staged once per block.
  __shared__ char wlds[32768];

  const int tid = threadIdx.x;
  const int wid = tid >> 6;
  const int l = tid & 63;
  const int c = l & 15;  // MFMA col (pixel slot)
  const int g = l >> 4;  // 4-lane group

  const f32x4 zz = {0.f, 0.f, 0.f, 0.f};

  const int pxB = blockIdx.x * 64 + wid * 16;  // 2048 blocks x 64 px
  const int b8 = pxB >> 14;
  const int blkBase = b8 * (kC * kHW);
  const int hw = (pxB & (kHW - 1)) + c;
  const float* __restrict__ hfp = hf + blkBase + hw;
  float* __restrict__ outp = out + blkBase + hw;

  const float rv = rscale[0];

  // ---------- stage weight table into LDS (wave w: bytes w*8K..w*8K+8K) ----
#pragma unroll
  for (int i = 0; i < 8; ++i) {
    __builtin_amdgcn_global_load_lds(
        (const __attribute__((address_space(1))) unsigned int*)(wfr +
                                                                wid * 8192 +
                                                                i * 1024 +
                                                                l * 16),
        (__attribute__((address_space(3))) unsigned int*)(wlds + wid * 8192 +
                                                          i * 1024),
        16, 0, 0);
  }

  // ---------- issue ALL 48 X loads, fence, convert ----------
  float xr[3][2][8];
#pragma unroll
  for (int b = 0; b < 3; ++b)
#pragma unroll
    for (int s = 0; s < 2; ++s)
#pragma unroll
      for (int j = 0; j < 8; ++j)
        xr[b][s][j] = hfp[(b * 64 + s * 32 + g * 8 + j) * kHW];
  __builtin_amdgcn_sched_barrier(0);  // all loads issue before any convert

  bf16x8 Xf[3][2];
#pragma unroll
  for (int b = 0; b < 3; ++b)
#pragma unroll
    for (int s = 0; s < 2; ++s) {
      bf16x8 xf;
#pragma unroll
      for (int j = 0; j < 8; ++j) xf[j] = (short)f2bf(xr[b][s][j]);
      Xf[b][s] = xf;
    }

  // weight table fully in LDS before any wave reads it
  asm volatile("s_waitcnt vmcnt(0)" ::: "memory");
  __syncthreads();

  // ---------- heads + in-register y relayout ----------
  const int srcA = ((g & 1) * 2) * 16 + c;
  const bool hi = (g >> 1) & 1;

  uint2 pkA[3], pkB[3];
  bf16x8 yS0[3], yS1[3];

  head_compute<0>(wlds, l, Xf, pkA);
  __builtin_amdgcn_sched_barrier(0);
  head_compute<1>(wlds, l, Xf, pkB);
  __builtin_amdgcn_sched_barrier(0);
#pragma unroll
  for (int b = 0; b < 3; ++b) yS0[b] = build_frag(pkA[b], pkB[b], srcA, hi);
  __builtin_amdgcn_sched_barrier(0);
  head_compute<2>(wlds, l, Xf, pkA);
  __builtin_amdgcn_sched_barrier(0);
  head_compute<3>(wlds, l, Xf, pkB);
  __builtin_amdgcn_sched_barrier(0);
#pragma unroll
  for (int b = 0; b < 3; ++b) yS1[b] = build_frag(pkA[b], pkB[b], srcA, hi);

  // ---------- epilogue: proj + residual-from-Xf ----------
  float bias_[4][4];
#pragma unroll
  for (int m = 0; m < 4; ++m) {
    const float4 bj = *(const float4*)(bproj + m * 16 + g * 4);
    bias_[m][0] = bj.x;
    bias_[m][1] = bj.y;
    bias_[m][2] = bj.z;
    bias_[m][3] = bj.w;
  }

#pragma unroll
  for (int b = 0; b < 3; ++b) {
#pragma unroll
    for (int m = 0; m < 4; ++m) {
      const bf16x8 pA0 =
          *(const bf16x8*)(wlds + (24 + m * 2 + 0) * 1024 + l * 16);
      const bf16x8 pA1 =
          *(const bf16x8*)(wlds + (24 + m * 2 + 1) * 1024 + l * 16);
      f32x4 o = __builtin_amdgcn_mfma_f32_16x16x32_bf16(pA0, yS0[b], zz, 0, 0, 0);
      o = __builtin_amdgcn_mfma_f32_16x16x32_bf16(pA1, yS1[b], o, 0, 0, 0);

      // residual from Xf via wave shuffles (all transient)
      union {
        bf16x8 v;
        unsigned u[4];
      } su;
      su.v = Xf[b][m >> 1];
      const int hl = ((m & 1) * 2 + (g >> 1)) * 16 + c;
      const unsigned w0 = (unsigned)__shfl((int)su.u[0], hl, 64);
      const unsigned w1 = (unsigned)__shfl((int)su.u[1], hl, 64);
      const unsigned w2 = (unsigned)__shfl((int)su.u[2], hl, 64);
      const unsigned w3 = (unsigned)__shfl((int)su.u[3], hl, 64);
      const unsigned lo = (g & 1) ? w2 : w0;  // channels j=0,1
      const unsigned hi2 = (g & 1) ? w3 : w1;  // channels j=2,3
      float res[4];
      res[0] = __uint_as_float(lo << 16);
      res[1] = __uint_as_float(lo & 0xffff0000u);
      res[2] = __uint_as_float(hi2 << 16);
      res[3] = __uint_as_float(hi2 & 0xffff0000u);

#pragma unroll
      for (int j = 0; j < 4; ++j) {
        outp[(b * 64 + m * 16 + g * 4 + j) * kHW] =
            fmaf(rv, o[j] + bias_[m][j], res[j]);
      }
    }
  }
}

extern "C" void kernel_launch(void* const* d_in, const int* in_sizes, int n_in,
                              void* d_out, int out_size, void* d_ws,
                              size_t ws_size, hipStream_t stream) {
  const float* hf = (const float*)d_in[0];
  const float* Wqkv = (const float*)d_in[1];
  const float* Wproj = (const float*)d_in[2];
  const float* bproj = (const float*)d_in[3];
  const float* rscale = (const float*)d_in[4];
  float* out = (float*)d_out;
  unsigned char* wsc = (unsigned char*)d_ws;

  hipLaunchKernelGGL(pack_weights, dim3(1), dim3(256), 0, stream, Wqkv, Wproj,
                     wsc);

  const int npix = in_sizes[0] / kC;  // 131072
  const int nblocks = npix / 64;      // 2048
  hipLaunchKernelGGL(hfattn_mfma10, dim3(nblocks), dim3(256), 0, stream, hf,
                     wsc, bproj, rscale, out);
}